// Round 2
// baseline (395.584 us; speedup 1.0000x reference)
//
#include <hip/hip_runtime.h>
#include <hip/hip_bf16.h>

typedef unsigned int uint;

// B=16, H=2048, NH=16, HD=128, S=4096, 3H=6144, FF=8192. All tensors f32.

// ---------------- LayerNorm (f32) ----------------
__global__ __launch_bounds__(256) void ln_f32_kernel(const float* __restrict__ in,
    const float* __restrict__ g, const float* __restrict__ bb, float* __restrict__ out)
{
    int row = blockIdx.x, t = threadIdx.x;
    const float* rp = in + row*2048;
    float4 a = ((const float4*)rp)[2*t];
    float4 b = ((const float4*)rp)[2*t+1];
    float v[8] = {a.x,a.y,a.z,a.w,b.x,b.y,b.z,b.w};
    float s=0.f, s2=0.f;
    #pragma unroll
    for(int i=0;i<8;i++){ s+=v[i]; s2+=v[i]*v[i]; }
    #pragma unroll
    for(int o=32;o>0;o>>=1){ s += __shfl_xor(s,o); s2 += __shfl_xor(s2,o); }
    __shared__ float red[8];
    int wv=t>>6, ln=t&63;
    if(ln==0){ red[wv]=s; red[4+wv]=s2; }
    __syncthreads();
    s  = red[0]+red[1]+red[2]+red[3];
    s2 = red[4]+red[5]+red[6]+red[7];
    float mu = s*(1.f/2048.f);
    float var = s2*(1.f/2048.f) - mu*mu;
    float rs = rsqrtf(var + 1e-5f);
    float4 g0 = ((const float4*)g)[2*t],  g1 = ((const float4*)g)[2*t+1];
    float4 b0 = ((const float4*)bb)[2*t], b1 = ((const float4*)bb)[2*t+1];
    float* op = out + row*2048 + t*8;
    float4 o0 = make_float4((v[0]-mu)*rs*g0.x+b0.x, (v[1]-mu)*rs*g0.y+b0.y,
                            (v[2]-mu)*rs*g0.z+b0.z, (v[3]-mu)*rs*g0.w+b0.w);
    float4 o1 = make_float4((v[4]-mu)*rs*g1.x+b1.x, (v[5]-mu)*rs*g1.y+b1.y,
                            (v[6]-mu)*rs*g1.z+b1.z, (v[7]-mu)*rs*g1.w+b1.w);
    ((float4*)op)[0]=o0; ((float4*)op)[1]=o1;
}

// ---------------- split-K skinny GEMM: part[kc][16][N] = X[16,K] * W[K,N] ----------------
// 256 threads, 2 cols/thread -> 512 cols per block. grid.x = colchunks*splitk
template<int KCHUNK>
__global__ __launch_bounds__(256) void gemm_sk(const float* __restrict__ X,
    const float* __restrict__ W, float* __restrict__ part, int K, int N, int colchunks)
{
    __shared__ float XS[16][KCHUNK];
    int cc = blockIdx.x % colchunks;
    int kc = blockIdx.x / colchunks;
    int k0 = kc * KCHUNK;
    for (int idx = threadIdx.x; idx < 16*KCHUNK; idx += 256){
        int m = idx / KCHUNK, i = idx % KCHUNK;
        XS[m][i] = X[m*K + k0 + i];
    }
    __syncthreads();
    int n0 = cc*512 + threadIdx.x*2;
    float a0[16], a1[16];
    #pragma unroll
    for(int m=0;m<16;m++){ a0[m]=0.f; a1[m]=0.f; }
    const float* Wp = W + (size_t)k0*N + n0;
    for (int i=0;i<KCHUNK;i+=4){
        float2 w0 = *(const float2*)(Wp + (size_t)(i+0)*N);
        float2 w1 = *(const float2*)(Wp + (size_t)(i+1)*N);
        float2 w2 = *(const float2*)(Wp + (size_t)(i+2)*N);
        float2 w3 = *(const float2*)(Wp + (size_t)(i+3)*N);
        #pragma unroll
        for(int m=0;m<16;m++){
            float4 x4 = *(const float4*)&XS[m][i];
            a0[m] += x4.x*w0.x + x4.y*w1.x + x4.z*w2.x + x4.w*w3.x;
            a1[m] += x4.x*w0.y + x4.y*w1.y + x4.z*w2.y + x4.w*w3.y;
        }
    }
    #pragma unroll
    for(int m=0;m<16;m++){
        *(float2*)&part[((size_t)(kc*16+m))*N + n0] = make_float2(a0[m], a1[m]);
    }
}

// ---------------- split-K reduce + bias + (residual / gelu / store) ----------------
// mode 0: out=sum+bias   mode 1: +residual   mode 2: gelu_new(sum+bias)   mode 3: +residual
__global__ __launch_bounds__(256) void reduce_sk(const float* __restrict__ part, int N, int splitk,
    const float* __restrict__ bias, const float* __restrict__ res,
    float* __restrict__ outf, int mode)
{
    int n = blockIdx.x*256 + threadIdx.x;
    int m = blockIdx.y;
    size_t stride = (size_t)16*N;
    const float* p = part + (size_t)m*N + n;
    float s = 0.f;
    for (int kc=0;kc<splitk;kc++) s += p[(size_t)kc*stride];
    s += bias[n];
    if (mode==1 || mode==3) s += res[m*N+n];
    if (mode==2){
        float x = s;
        float t = tanhf(0.7978845608028654f*(x + 0.044715f*x*x*x));
        s = 0.5f*x*(1.f+t);
    }
    outf[m*N+n] = s;
}

// ---------------- flash-decode attention: per-wave key chunks of 128 ----------------
// grid (8, NH, B), 256 thr (4 waves). wave-chunk wc = blockIdx.x*4+wave handles keys
// [wc*128, wc*128+128) (wc==31 also key 4096 = new token). Partials: (m,l,o[128]).
__global__ __launch_bounds__(256) void attn_chunk(const float* __restrict__ qkv,
    const float* __restrict__ Kc, const float* __restrict__ Vc, float* __restrict__ part)
{
    int h = blockIdx.y, b = blockIdx.z;
    int wave = threadIdx.x >> 6, lane = threadIdx.x & 63;
    int wc = blockIdx.x*4 + wave;            // 0..31
    int jstart = wc * 128;
    const float* qrow = qkv + b*6144 + h*128;
    float2 q = *(const float2*)(qrow + 2*lane);
    size_t bh = (size_t)(b*16+h);
    const float* kp = Kc + bh*4096*128 + (size_t)jstart*128 + 2*lane;
    const float* vp = Vc + bh*4096*128 + (size_t)jstart*128 + 2*lane;
    float m = -1e30f, l = 0.f, o0 = 0.f, o1 = 0.f;
    #pragma unroll 4
    for (int j=0;j<128;++j){
        float2 kw = *(const float2*)kp;
        float2 vw = *(const float2*)vp;
        kp += 128; vp += 128;
        float p = q.x*kw.x + q.y*kw.y;
        p += __shfl_xor(p,32); p += __shfl_xor(p,16); p += __shfl_xor(p,8);
        p += __shfl_xor(p,4);  p += __shfl_xor(p,2);  p += __shfl_xor(p,1);
        float sc = p * 0.08838834764831845f;
        float mn = fmaxf(m, sc);
        float f  = __expf(m - mn);
        float e  = __expf(sc - mn);
        l  = l*f + e;
        o0 = o0*f + e*vw.x;
        o1 = o1*f + e*vw.y;
        m = mn;
    }
    if (wc == 31){ // new-token key/value (from qkv buffer)
        const float* kn = qkv + b*6144 + 2048 + h*128;
        const float* vn = qkv + b*6144 + 4096 + h*128;
        float p = q.x*kn[2*lane] + q.y*kn[2*lane+1];
        p += __shfl_xor(p,32); p += __shfl_xor(p,16); p += __shfl_xor(p,8);
        p += __shfl_xor(p,4);  p += __shfl_xor(p,2);  p += __shfl_xor(p,1);
        float sc = p * 0.08838834764831845f;
        float mn = fmaxf(m, sc);
        float f  = __expf(m - mn);
        float e  = __expf(sc - mn);
        l  = l*f + e;
        o0 = o0*f + e*vn[2*lane];
        o1 = o1*f + e*vn[2*lane+1];
        m = mn;
    }
    float* pp = part + ((size_t)(b*16+h)*32 + wc)*132;
    if (lane==0){ pp[0]=m; pp[1]=l; }
    *(float2*)&pp[2+2*lane] = make_float2(o0,o1);
}

__global__ __launch_bounds__(64) void attn_combine(const float* __restrict__ part,
                                                   float* __restrict__ attn_out)
{
    int bh = blockIdx.x;      // 0..255
    int lane = threadIdx.x;   // 64
    const float* pp = part + (size_t)bh*32*132;
    float M = -1e30f;
    for (int kc=0;kc<32;kc++) M = fmaxf(M, pp[kc*132]);
    float den=0.f, a0=0.f, a1=0.f;
    for (int kc=0;kc<32;kc++){
        float f = __expf(pp[kc*132] - M);
        den += f * pp[kc*132+1];
        float2 o = *(const float2*)&pp[kc*132 + 2 + 2*lane];
        a0 += f*o.x; a1 += f*o.y;
    }
    float inv = 1.f/den;
    int b = bh>>4, h = bh&15;
    float* op = attn_out + b*2048 + h*128 + 2*lane;
    op[0]=a0*inv; op[1]=a1*inv;
}

extern "C" void kernel_launch(void* const* d_in, const int* in_sizes, int n_in,
                              void* d_out, int out_size, void* d_ws, size_t ws_size,
                              hipStream_t stream)
{
    const float* hid  = (const float*)d_in[0];
    const float* Kc   = (const float*)d_in[1];
    const float* Vc   = (const float*)d_in[2];
    const float* ln1g = (const float*)d_in[3];
    const float* ln1b = (const float*)d_in[4];
    const float* Wqkv = (const float*)d_in[5];
    const float* bqkv = (const float*)d_in[6];
    const float* Wproj= (const float*)d_in[7];
    const float* bproj= (const float*)d_in[8];
    const float* ln2g = (const float*)d_in[9];
    const float* ln2b = (const float*)d_in[10];
    const float* Wfc  = (const float*)d_in[11];
    const float* bfc  = (const float*)d_in[12];
    const float* Wout = (const float*)d_in[13];
    const float* bout = (const float*)d_in[14];

    float* ws      = (float*)d_ws;
    float* xln     = ws;                    // 32768
    float* qkv     = xln + 32768;           // 98304
    float* attn_o  = qkv + 98304;           // 32768
    float* hbuf    = attn_o + 32768;        // 32768
    float* yln     = hbuf + 32768;          // 32768
    float* act     = yln + 32768;           // 131072
    float* apart   = act + 131072;          // 16*16*32*132 = 1081344
    float* gpart   = apart + 1081344;       // up to 4194304

    // 1. LN1
    ln_f32_kernel<<<16,256,0,stream>>>(hid, ln1g, ln1b, xln);
    // 2. QKV = xln @ Wqkv + b   (K=2048, N=6144, splitk=32)
    gemm_sk<64><<<12*32,256,0,stream>>>(xln, Wqkv, gpart, 2048, 6144, 12);
    reduce_sk<<<dim3(24,16),256,0,stream>>>(gpart, 6144, 32, bqkv, nullptr, qkv, 0);
    // 3. attention
    attn_chunk<<<dim3(8,16,16),256,0,stream>>>(qkv, Kc, Vc, apart);
    attn_combine<<<256,64,0,stream>>>(apart, attn_o);
    // 4. proj + residual (K=2048, N=2048, splitk=32)
    gemm_sk<64><<<4*32,256,0,stream>>>(attn_o, Wproj, gpart, 2048, 2048, 4);
    reduce_sk<<<dim3(8,16),256,0,stream>>>(gpart, 2048, 32, bproj, hid, hbuf, 1);
    // 5. LN2
    ln_f32_kernel<<<16,256,0,stream>>>(hbuf, ln2g, ln2b, yln);
    // 6. FC + gelu (K=2048, N=8192, splitk=32)
    gemm_sk<64><<<16*32,256,0,stream>>>(yln, Wfc, gpart, 2048, 8192, 16);
    reduce_sk<<<dim3(32,16),256,0,stream>>>(gpart, 8192, 32, bfc, nullptr, act, 2);
    // 7. OUT + residual -> f32 d_out (K=8192, N=2048, splitk=64, kchunk=128)
    gemm_sk<128><<<4*64,256,0,stream>>>(act, Wout, gpart, 8192, 2048, 4);
    reduce_sk<<<dim3(8,16),256,0,stream>>>(gpart, 2048, 64, bout, hbuf, (float*)d_out, 3);
    (void)in_sizes; (void)n_in; (void)out_size; (void)ws_size;
}